// Round 4
// baseline (130.183 us; speedup 1.0000x reference)
//
#include <hip/hip_runtime.h>
#include <math.h>

#define BQ 128
#define NQ 256
#define SMAX 300
#define CCLS 5
#define CCHG 3
#define TSTR 268          // s_tab row stride (floats), cc-major [15][268]
#define RSTR 12           // s_rows row stride (floats)
#define INFV 3.0e38f

#define NBLK 256          // 2 blocks per batch (row-halves); grid == 256 CUs
                          // -> every block fits a CU alone => all co-resident,
                          //    partner-flag spin cannot deadlock.

// ws layout (floats/words); ~290 KB, all written before read each iteration.
// Only h==1 halves publish partials; h==0 keeps its own in LDS/regs.
#define W_COL 0           // [128][256] h1 col-min partials
#define W_SC  32768       // [128]      h1 row-min-sum partial
#define W_SS  32896       // [128][304] h1 ss column-sum partials
#define W_B   71808       // [128]      per-batch totals
#define W_FA  71936       // [128]      h1-ready flag A
#define W_FB  72064       // [128]      h1-ready flag B
#define W_GA  72192       // [128]      batch-total-ready flag A
#define W_GB  72320       // [128]      batch-total-ready flag B

// Non-uniform-byte magics: a byte-pattern (or word-pattern) poison fill
// cannot reproduce two DIFFERENT non-uniform words, so garbage can never
// fake a completed handshake. Fresh poison each iteration resets them.
#define MAGIC_A 0x1F2E3D4Cu
#define MAGIC_B 0xC4D3E2F1u
#define MAGIC_C 0x0A1B2C3Du
#define MAGIC_D 0xD3C2B1A0u

// LDS (floats)
#define P_TAB   0         // 15*268 NLL table (cc-major); reused by combine
#define P_COLS  4020      // 256*8 pflow pos/mom/en
#define P_ROWS  6068      // 128*12 particle rows of this half
#define P_RED   7604      // [16][128] row-min partials over ty
#define P_PART  9652      // [2]
#define P_OWNC  9656      // [256] own col-min partial
#define P_OWNS  9912      // [304] own ss column partial
#define SMEM_FLOATS 10216

__device__ __forceinline__ float fast_sqrtf(float x) {
    return __builtin_amdgcn_sqrtf(x);
}

__device__ __forceinline__ void pub(unsigned int* p, unsigned int v) {
    __hip_atomic_store(p, v, __ATOMIC_RELEASE, __HIP_MEMORY_SCOPE_AGENT);
}
__device__ __forceinline__ unsigned int seen(const unsigned int* p) {
    return __hip_atomic_load(p, __ATOMIC_ACQUIRE, __HIP_MEMORY_SCOPE_AGENT);
}

__global__ __launch_bounds__(512, 2) void main_kernel(
    const int* __restrict__ p_class, const int* __restrict__ p_charge,
    const int* __restrict__ n_particles,
    const float* __restrict__ cls_logits, const float* __restrict__ chg_logits,
    const float* __restrict__ p_pos, const float* __restrict__ pf_pos,
    const float* __restrict__ p_mom, const float* __restrict__ pf_mom,
    const float* __restrict__ p_en, const float* __restrict__ pf_en,
    const float* __restrict__ setsizes, float* __restrict__ ws,
    float* __restrict__ out, int out_size)
{
    __shared__ float smem[SMEM_FLOATS];
    const int t   = threadIdx.x;
    const int blk = blockIdx.x;
    const int b   = blk >> 1;         // batch
    const int h   = blk & 1;          // row-half
    const int base = b * NQ;
    unsigned int* wsu = (unsigned int*)ws;

    float* s_tab  = smem + P_TAB;
    float* s_cols = smem + P_COLS;
    float* s_rows = smem + P_ROWS;
    float* s_red  = smem + P_RED;
    float* s_part = smem + P_PART;
    float* s_ownc = smem + P_OWNC;
    float* s_owns = smem + P_OWNS;

    // ---------------- phase A: this row-half's pair work + ss half-stream ---
    if (t < NQ) {
        // NLL table column t (pflow logits) + pflow col data
        const int gj = base + t;
        const float* cl = cls_logits + (size_t)gj * CCLS;
        float l0=cl[0], l1=cl[1], l2=cl[2], l3=cl[3], l4=cl[4];
        float mx = fmaxf(fmaxf(fmaxf(l0,l1),fmaxf(l2,l3)),l4);
        float lse = mx + __logf(__expf(l0-mx)+__expf(l1-mx)+__expf(l2-mx)+
                                __expf(l3-mx)+__expf(l4-mx));
        const float* gl = chg_logits + (size_t)gj * CCHG;
        float g0=gl[0], g1=gl[1], g2=gl[2];
        float gmx = fmaxf(fmaxf(g0,g1),g2);
        float glse = gmx + __logf(__expf(g0-gmx)+__expf(g1-gmx)+__expf(g2-gmx));
        float nc[CCLS] = {lse-l0, lse-l1, lse-l2, lse-l3, lse-l4};
        float ng[CCHG] = {glse-g0, glse-g1, glse-g2};
        #pragma unroll
        for (int c = 0; c < CCLS; ++c)
            #pragma unroll
            for (int g = 0; g < CCHG; ++g)
                s_tab[(c*CCHG+g)*TSTR + t] = nc[c] + ng[g];

        float* cr = &s_cols[t*8];
        cr[0]=pf_pos[gj*3+0]; cr[1]=pf_pos[gj*3+1]; cr[2]=pf_pos[gj*3+2];
        cr[3]=pf_mom[gj*3+0]; cr[4]=pf_mom[gj*3+1]; cr[5]=pf_mom[gj*3+2];
        cr[6]=pf_en[gj];      cr[7]=0.0f;
    } else if (t < NQ + 128) {
        // particle row rr of this half
        const int rr = t - NQ;
        const int gr = base + h*128 + rr;
        float* rw = &s_rows[rr*RSTR];
        rw[0]=p_pos[gr*3+0]; rw[1]=p_pos[gr*3+1]; rw[2]=p_pos[gr*3+2];
        rw[3]=p_mom[gr*3+0]; rw[4]=p_mom[gr*3+1]; rw[5]=p_mom[gr*3+2];
        rw[6]=p_en[gr];
        rw[7]=__int_as_float(p_class[gr]*CCHG + p_charge[gr]);
    }
    __syncthreads();

    const int tx = t & 31;    // local rows tx + 32r, r<4 (128 rows of this half)
    const int ty = t >> 5;    // cols ty*16 + c
    const int c0 = ty * 16;

    float4 ra[4], rb[4];
    int ccr[4];
    #pragma unroll
    for (int r = 0; r < 4; ++r) {
        const int row = tx + 32*r;
        ra[r] = *(const float4*)&s_rows[row*RSTR];
        rb[r] = *(const float4*)&s_rows[row*RSTR + 4];
        ccr[r] = __float_as_int(rb[r].w) * TSTR;
    }
    float rmin[4] = {INFV, INFV, INFV, INFV};

    // ss streaming state: this half's 128 rows, col = t (t < 300)
    const bool ssa = (t < SMAX);
    const float* ssp = setsizes + ((size_t)base + (size_t)(h*128)) * SMAX + t;
    float ssacc = 0.0f;

    // 4 chunks: {issue 32 ss loads} -> {4 pair columns} -> {consume ss loads}
    #pragma unroll 1
    for (int chunk = 0; chunk < 4; ++chunk) {
        float ssv[32];
        if (ssa) {
            #pragma unroll
            for (int u = 0; u < 32; ++u)
                ssv[u] = ssp[(size_t)(chunk*32 + u) * SMAX];
        }

        float cm[4] = {INFV, INFV, INFV, INFV};
        #pragma unroll
        for (int cc = 0; cc < 4; ++cc) {
            const int j = c0 + chunk*4 + cc;
            const float4 cd0 = *(const float4*)&s_cols[j*8];   // half-wave bcast
            const float4 cd1 = *(const float4*)&s_cols[j*8+4];
            #pragma unroll
            for (int r = 0; r < 4; ++r) {
                float dx=ra[r].x-cd0.x, dy=ra[r].y-cd0.y, dz=ra[r].z-cd0.z;
                float ex=ra[r].w-cd0.w, ey=rb[r].x-cd1.x, ez=rb[r].y-cd1.y;
                float de=rb[r].z-cd1.z;
                float v = s_tab[ccr[r] + j]                    // <=15 rows, bcast
                        + fast_sqrtf(dx*dx + dy*dy + dz*dz)
                        + fast_sqrtf(ex*ex + ey*ey + ez*ez)
                        + de*de;
                rmin[r] = fminf(rmin[r], v);
                cm[cc]  = fminf(cm[cc], v);
            }
        }

        // col-min partial (over this half's 128 rows)
        #pragma unroll
        for (int cc = 0; cc < 4; ++cc) {
            float v = cm[cc];
            #pragma unroll
            for (int off = 16; off > 0; off >>= 1)
                v = fminf(v, __shfl_down(v, off, 32));
            if (tx == 0) {
                s_ownc[c0 + chunk*4 + cc] = v;
                if (h) ws[W_COL + b*NQ + c0 + chunk*4 + cc] = v;
            }
        }

        if (ssa) {
            #pragma unroll
            for (int u = 0; u < 32; ++u) ssacc += ssv[u];
        }
    }

    // ss column partial
    if (ssa) {
        s_owns[t] = ssacc;
        if (h) ws[W_SS + b*304 + t] = ssacc;
    }

    // row-min partials over ty -> LDS -> complete row mins -> sum
    #pragma unroll
    for (int r = 0; r < 4; ++r)
        s_red[ty*128 + tx + 32*r] = rmin[r];
    __syncthreads();
    if (t < 128) {
        float m = s_red[t];
        #pragma unroll
        for (int k = 1; k < 16; ++k) m = fminf(m, s_red[k*128 + t]);
        #pragma unroll
        for (int off = 32; off > 0; off >>= 1) m += __shfl_down(m, off, 64);
        if ((t & 63) == 0) s_part[t >> 6] = m;
    }
    __syncthreads();          // all LDS + ws writes of this block complete

    float rs = s_part[0] + s_part[1];    // this half's row-min sum (all threads)

    // ---------------- phase B: handshake + per-batch combine ----------------
    if (h) {
        // producer: publish row-sum + ready flags, then exit
        if (t == 0) {
            ws[W_SC + b] = rs;
            __threadfence();
            pub(&wsu[W_FA + b], MAGIC_A);
            pub(&wsu[W_FB + b], MAGIC_B);
        }
        return;
    }

    // consumer (h==0): wait for partner
    if (t == 0) {
        while (seen(&wsu[W_FA + b]) != MAGIC_A ||
               seen(&wsu[W_FB + b]) != MAGIC_B) { }
        __threadfence();
    }
    __syncthreads();

    // combine-phase LDS (reuses the dead s_tab region)
    float* s_m   = smem;          // [304]
    float* s_p   = smem + 304;    // [8]
    float* s_q   = smem + 312;    // [8]
    float* s_one = smem + 320;    // [1]
    const int wave = t >> 6, lane = t & 63;

    // col-min combine + sum
    float v = 0.0f;
    if (t < NQ)
        v = fminf(s_ownc[t], ws[W_COL + b*NQ + t]);
    #pragma unroll
    for (int off = 32; off > 0; off >>= 1) v += __shfl_down(v, off, 64);
    if (lane == 0) s_p[wave] = v;

    // ss combine + softmax
    float m = -INFV;
    if (t < SMAX) {
        m = (s_owns[t] + ws[W_SS + b*304 + t]) * (1.0f / NQ);
        s_m[t] = m;
    }
    float wm = m;
    #pragma unroll
    for (int off = 32; off > 0; off >>= 1) wm = fmaxf(wm, __shfl_down(wm, off, 64));
    if (lane == 0) s_q[wave] = wm;
    __syncthreads();
    if (t == 0) {
        float a = fmaxf(fmaxf(s_q[0], s_q[1]), fmaxf(s_q[2], s_q[3]));
        float c = fmaxf(fmaxf(s_q[4], s_q[5]), fmaxf(s_q[6], s_q[7]));
        s_one[0] = fmaxf(a, c);
    }
    __syncthreads();
    const float mx = s_one[0];
    float e = (t < SMAX) ? __expf(m - mx) : 0.0f;
    #pragma unroll
    for (int off = 32; off > 0; off >>= 1) e += __shfl_down(e, off, 64);
    if (lane == 0) s_q[wave] = e;      // old s_q consumed above
    __syncthreads();
    if (t == 0) {
        float S = s_q[0]+s_q[1]+s_q[2]+s_q[3]+s_q[4]+s_q[5]+s_q[6]+s_q[7];
        float colsum = s_p[0]+s_p[1]+s_p[2]+s_p[3]+s_p[4]+s_p[5]+s_p[6]+s_p[7];
        int nb = n_particles[b];
        float ssl = -(s_m[nb] - mx - __logf(S));
        float total = colsum + rs + ws[W_SC + b] + ssl;
        ws[W_B + b] = total;
        __threadfence();
        pub(&wsu[W_GA + b], MAGIC_C);
        pub(&wsu[W_GB + b], MAGIC_D);
    }

    // ---------------- phase C: block 0 collects the 128 batch totals --------
    if (blk != 0) return;

    int ok;
    do {
        int mine = 1;
        if (t < BQ)
            mine = (seen(&wsu[W_GA + t]) == MAGIC_C) &&
                   (seen(&wsu[W_GB + t]) == MAGIC_D);
        ok = __syncthreads_and(mine);
    } while (!ok);
    __threadfence();

    float tv = (t < BQ) ? ws[W_B + t] : 0.0f;
    #pragma unroll
    for (int off = 32; off > 0; off >>= 1) tv += __shfl_down(tv, off, 64);
    if (lane == 0 && wave < 2) s_p[wave] = tv;
    __syncthreads();
    if (t == 0) out[0] = (s_p[0] + s_p[1]) * (1.0f / BQ);
    // zero any padded tail of the output buffer
    for (int i = 1 + t; i < out_size && i < 1024; i += 512) out[i] = 0.0f;
}

extern "C" void kernel_launch(void* const* d_in, const int* in_sizes, int n_in,
                              void* d_out, int out_size, void* d_ws, size_t ws_size,
                              hipStream_t stream) {
    (void)in_sizes; (void)n_in; (void)ws_size;
    const int*   p_class     = (const int*)d_in[0];
    const int*   p_charge    = (const int*)d_in[1];
    const int*   n_particles = (const int*)d_in[2];
    const float* cls_logits  = (const float*)d_in[3];
    const float* chg_logits  = (const float*)d_in[4];
    const float* p_pos       = (const float*)d_in[5];
    const float* pf_pos      = (const float*)d_in[6];
    const float* p_mom       = (const float*)d_in[7];
    const float* pf_mom      = (const float*)d_in[8];
    const float* p_en        = (const float*)d_in[9];
    const float* pf_en       = (const float*)d_in[10];
    const float* setsizes    = (const float*)d_in[11];
    float* out = (float*)d_out;
    float* ws  = (float*)d_ws;   // ~290 KB used, all written before read

    main_kernel<<<NBLK, 512, 0, stream>>>(
        p_class, p_charge, n_particles, cls_logits, chg_logits,
        p_pos, pf_pos, p_mom, pf_mom, p_en, pf_en, setsizes, ws, out, out_size);
}

// Round 5
// 109.269 us; speedup vs baseline: 1.1914x; 1.1914x over previous
//
#include <hip/hip_runtime.h>
#include <math.h>

#define BQ 128
#define NQ 256
#define SMAX 300
#define CCLS 5
#define CCHG 3
#define TSTR 268          // s_tab row stride (floats), cc-major [15][268]
#define RSTR 12           // s_rows row stride (floats)
#define INFV 3.0e38f

#define NPAIR 128         // full-batch pair blocks (256 rows x 256 cols each)
#define NMAIN (NPAIR + BQ)

__device__ __forceinline__ float fast_sqrtf(float x) {
    return __builtin_amdgcn_sqrtf(x);
}

// pair-block LDS (floats):
//  s_tab  : [0,4020)        15*268 NLL table (cc-major)
//  s_cols : [4020,6068)     256*8  pflow pos/mom/en
//  s_rows : [6068,9140)     256*12 ALL particle rows of the batch
//  s_red  : [9140,11188)    [16][128] row-min partials over ty
//  s_part : [11188,11212)   [0..15] col-sum partials, [20..23] row partials
// ss blocks reuse the front of the same array (~1 KB).
#define P_TAB   0
#define P_COLS  4020
#define P_ROWS  6068
#define P_RED   9140
#define P_PART  11188
#define SMEM_FLOATS 11212

__global__ __launch_bounds__(512, 2) void main_kernel(
    const int* __restrict__ p_class, const int* __restrict__ p_charge,
    const int* __restrict__ n_particles,
    const float* __restrict__ cls_logits, const float* __restrict__ chg_logits,
    const float* __restrict__ p_pos, const float* __restrict__ pf_pos,
    const float* __restrict__ p_mom, const float* __restrict__ pf_mom,
    const float* __restrict__ p_en, const float* __restrict__ pf_en,
    const float* __restrict__ setsizes, float* __restrict__ out)
{
    __shared__ float smem[SMEM_FLOATS];
    const int t = threadIdx.x;
    const int blk = blockIdx.x;

    if (blk < NPAIR) {
        // ---------------- pair block: full batch, 256 rows x 256 cols -----
        const int b    = blk;
        const int base = b * NQ;
        float* s_tab  = smem + P_TAB;
        float* s_cols = smem + P_COLS;
        float* s_rows = smem + P_ROWS;
        float* s_red  = smem + P_RED;
        float* s_part = smem + P_PART;

        if (t < NQ) {
            // NLL table column t (pflow logits) + pflow col data
            const int gj = base + t;
            const float* cl = cls_logits + (size_t)gj * CCLS;
            float l0=cl[0], l1=cl[1], l2=cl[2], l3=cl[3], l4=cl[4];
            float mx = fmaxf(fmaxf(fmaxf(l0,l1),fmaxf(l2,l3)),l4);
            float lse = mx + __logf(__expf(l0-mx)+__expf(l1-mx)+__expf(l2-mx)+
                                    __expf(l3-mx)+__expf(l4-mx));
            const float* gl = chg_logits + (size_t)gj * CCHG;
            float g0=gl[0], g1=gl[1], g2=gl[2];
            float gmx = fmaxf(fmaxf(g0,g1),g2);
            float glse = gmx + __logf(__expf(g0-gmx)+__expf(g1-gmx)+__expf(g2-gmx));
            float nc[CCLS] = {lse-l0, lse-l1, lse-l2, lse-l3, lse-l4};
            float ng[CCHG] = {glse-g0, glse-g1, glse-g2};
            #pragma unroll
            for (int c = 0; c < CCLS; ++c)
                #pragma unroll
                for (int g = 0; g < CCHG; ++g)
                    s_tab[(c*CCHG+g)*TSTR + t] = nc[c] + ng[g];

            float* cr = &s_cols[t*8];
            cr[0]=pf_pos[gj*3+0]; cr[1]=pf_pos[gj*3+1]; cr[2]=pf_pos[gj*3+2];
            cr[3]=pf_mom[gj*3+0]; cr[4]=pf_mom[gj*3+1]; cr[5]=pf_mom[gj*3+2];
            cr[6]=pf_en[gj];      cr[7]=0.0f;
        } else {
            // particle row rr (0..255) of the batch
            const int rr = t - NQ;
            const int gr = base + rr;
            float* rw = &s_rows[rr*RSTR];
            rw[0]=p_pos[gr*3+0]; rw[1]=p_pos[gr*3+1]; rw[2]=p_pos[gr*3+2];
            rw[3]=p_mom[gr*3+0]; rw[4]=p_mom[gr*3+1]; rw[5]=p_mom[gr*3+2];
            rw[6]=p_en[gr];
            rw[7]=__int_as_float(p_class[gr]*CCHG + p_charge[gr]);
        }
        __syncthreads();

        const int tx = t & 31;    // local rows tx + 32r, r<4 (per row-half)
        const int ty = t >> 5;    // cols ty*16 + c
        const int c0 = ty * 16;

        float cmin[16];
        #pragma unroll
        for (int c = 0; c < 16; ++c) cmin[c] = INFV;

        #pragma unroll 1
        for (int rh = 0; rh < 2; ++rh) {
            float4 ra[4], rb[4];
            int ccr[4];
            #pragma unroll
            for (int r = 0; r < 4; ++r) {
                const int row = rh*128 + tx + 32*r;
                ra[r] = *(const float4*)&s_rows[row*RSTR];
                rb[r] = *(const float4*)&s_rows[row*RSTR + 4];
                ccr[r] = __float_as_int(rb[r].w) * TSTR;
            }
            float rmin[4] = {INFV, INFV, INFV, INFV};

            #pragma unroll 4
            for (int c = 0; c < 16; ++c) {
                const int j = c0 + c;
                const float4 cd0 = *(const float4*)&s_cols[j*8];   // half-wave bcast
                const float4 cd1 = *(const float4*)&s_cols[j*8+4];
                float cm = cmin[c];
                #pragma unroll
                for (int r = 0; r < 4; ++r) {
                    float dx=ra[r].x-cd0.x, dy=ra[r].y-cd0.y, dz=ra[r].z-cd0.z;
                    float ex=ra[r].w-cd0.w, ey=rb[r].x-cd1.x, ez=rb[r].y-cd1.y;
                    float de=rb[r].z-cd1.z;
                    float v = s_tab[ccr[r] + j]                    // <=15 rows, bcast
                            + fast_sqrtf(dx*dx + dy*dy + dz*dz)
                            + fast_sqrtf(ex*ex + ey*ey + ez*ez)
                            + de*de;
                    rmin[r] = fminf(rmin[r], v);
                    cm = fminf(cm, v);
                }
                cmin[c] = cm;
            }

            // row-min partials over ty -> LDS, reduce this row-half
            #pragma unroll
            for (int r = 0; r < 4; ++r)
                s_red[ty*128 + tx + 32*r] = rmin[r];
            __syncthreads();
            if (t < 128) {
                float m = s_red[t];
                #pragma unroll
                for (int k = 1; k < 16; ++k) m = fminf(m, s_red[k*128 + t]);
                #pragma unroll
                for (int off = 32; off > 0; off >>= 1) m += __shfl_down(m, off, 64);
                if ((t & 63) == 0) s_part[20 + rh*2 + (t >> 6)] = m;
            }
            __syncthreads();   // s_red reused by next row-half
        }

        // col-min is now complete over all 256 rows: reduce across tx, sum cols
        float colsum = 0.0f;
        #pragma unroll
        for (int c = 0; c < 16; ++c) {
            float v = cmin[c];
            #pragma unroll
            for (int off = 16; off > 0; off >>= 1)
                v = fminf(v, __shfl_down(v, off, 32));
            colsum += v;                 // valid on tx==0
        }
        if (tx == 0) s_part[ty] = colsum;
        __syncthreads();
        if (t == 0) {
            float cs = 0.0f;
            #pragma unroll
            for (int k = 0; k < 16; ++k) cs += s_part[k];
            float rs = s_part[20] + s_part[21] + s_part[22] + s_part[23];
            atomicAdd(out, (cs + rs) * (1.0f / BQ));
        }

    } else {
        // ---------------- set-size block (one per batch, complete) --------
        const int b = blk - NPAIR;
        float* s_ss = smem;          // [2][304]
        float* s_m  = smem + 608;    // [304]
        float* s_p5 = smem + 912;    // [8]
        float* s_one= smem + 920;

        const int slice = t >> 8;    // 0/1 -> rows slice*128..+128
        const int col = t & 255;
        const float* bp = setsizes + (size_t)b * NQ * SMAX + (size_t)(slice*128) * SMAX;
        {
            const float* p = bp + col;
            float acc = 0.f;
            #pragma unroll 16
            for (int i = 0; i < 128; ++i) acc += p[(size_t)i * SMAX];
            s_ss[slice*304 + col] = acc;
        }
        if (col < SMAX - NQ) {       // cols 256..299
            const float* p = bp + (NQ + col);
            float acc = 0.f;
            #pragma unroll 16
            for (int i = 0; i < 128; ++i) acc += p[(size_t)i * SMAX];
            s_ss[slice*304 + NQ + col] = acc;
        }
        __syncthreads();
        float m = -INFV;
        if (t < SMAX) { m = (s_ss[t] + s_ss[304 + t]) * (1.0f / NQ); s_m[t] = m; }
        const int wave = t >> 6, lane = t & 63;
        float wm = m;
        #pragma unroll
        for (int off = 32; off > 0; off >>= 1) wm = fmaxf(wm, __shfl_down(wm, off));
        if (lane == 0 && wave < 5) s_p5[wave] = wm;
        __syncthreads();
        if (t == 0)
            s_one[0] = fmaxf(fmaxf(fmaxf(s_p5[0], s_p5[1]), fmaxf(s_p5[2], s_p5[3])), s_p5[4]);
        __syncthreads();
        const float mx = s_one[0];
        float e = (t < SMAX) ? __expf(m - mx) : 0.f;
        #pragma unroll
        for (int off = 32; off > 0; off >>= 1) e += __shfl_down(e, off);
        if (lane == 0 && wave < 5) s_p5[wave] = e;
        __syncthreads();
        if (t == 0) {
            float s = s_p5[0] + s_p5[1] + s_p5[2] + s_p5[3] + s_p5[4];
            int nb = n_particles[b];
            float loss = -(s_m[nb] - mx - __logf(s));
            atomicAdd(out, loss * (1.0f / BQ));
        }
    }
}

extern "C" void kernel_launch(void* const* d_in, const int* in_sizes, int n_in,
                              void* d_out, int out_size, void* d_ws, size_t ws_size,
                              hipStream_t stream) {
    (void)in_sizes; (void)n_in; (void)d_ws; (void)ws_size;
    const int*   p_class     = (const int*)d_in[0];
    const int*   p_charge    = (const int*)d_in[1];
    const int*   n_particles = (const int*)d_in[2];
    const float* cls_logits  = (const float*)d_in[3];
    const float* chg_logits  = (const float*)d_in[4];
    const float* p_pos       = (const float*)d_in[5];
    const float* pf_pos      = (const float*)d_in[6];
    const float* p_mom       = (const float*)d_in[7];
    const float* pf_mom      = (const float*)d_in[8];
    const float* p_en        = (const float*)d_in[9];
    const float* pf_en       = (const float*)d_in[10];
    const float* setsizes    = (const float*)d_in[11];
    float* out = (float*)d_out;

    // Only out[0] is accumulated into; zero at most 4 KB so a padded output
    // buffer never costs a full-buffer fill inside the timed region.
    size_t zb = (size_t)out_size * sizeof(float);
    if (zb > 4096) zb = 4096;
    (void)hipMemsetAsync(out, 0, zb, stream);

    main_kernel<<<NMAIN, 512, 0, stream>>>(
        p_class, p_charge, n_particles, cls_logits, chg_logits,
        p_pos, pf_pos, p_mom, pf_mom, p_en, pf_en, setsizes, out);
}